// Round 10
// baseline (180.187 us; speedup 1.0000x reference)
//
#include <hip/hip_runtime.h>
#include <math.h>

#define NN 50000
#define EE 800000
#define TOT (EE + NN)          // 850000 edges incl. self loops
#define CC 128
#define HH 4
#define HCW 512                // H*C
#define SCAN_B 196             // ceil(NN/256)
#define RB 64                  // rows per gemm block
#define GEMB ((NN + RB - 1) / RB)        // 782 gemm blocks
#define CNTB ((TOT + 511) / 512)         // 1661 count blocks

typedef short s16x8 __attribute__((ext_vector_type(8)));
typedef float f32x4 __attribute__((ext_vector_type(4)));
typedef float f32x2 __attribute__((ext_vector_type(2)));

// fp32 -> bf16 bits, round-to-nearest-even
__device__ __forceinline__ unsigned f2bf(float f) {
    unsigned u = __float_as_uint(f);
    return (u + 0x7fffu + ((u >> 16) & 1u)) >> 16;
}

// -------- P2: W [128][512] fp32 -> Wt [512][128] bf16 --------
__global__ __launch_bounds__(256) void k_prep_w(
    const float* __restrict__ W, unsigned short* __restrict__ wt)
{
    const int i = blockIdx.x * 256 + threadIdx.x;   // i = c*128 + k
    if (i >= HCW * CC) return;
    const int c = i >> 7, k = i & 127;
    wt[i] = (unsigned short)f2bf(W[(size_t)k * HCW + c]);
}

// -------- K1 (fat): blocks [0,GEMB) = MFMA gemm -> fp8 xh + fused att;
//                    blocks [GEMB, GEMB+CNTB) = degree count --------
__global__ __launch_bounds__(512, 4) void k_fat(
    const float* __restrict__ x,             // [NN][128] fp32
    const unsigned short* __restrict__ wt,   // [512][128] bf16 = W^T
    const float* __restrict__ att_s, const float* __restrict__ att_d,
    const int* __restrict__ ei,
    unsigned char* __restrict__ xhq,         // [NN][512] fp8 e4m3
    float* __restrict__ asrc, float* __restrict__ adst,
    int* __restrict__ deg, unsigned short* __restrict__ pos)
{
    __shared__ unsigned short xs[RB][CC + 8];   // 64x136 bf16
    __shared__ float red[8][2][4][16];          // [wave][src/dst][rt][row]

    if (blockIdx.x >= GEMB) {
        // ---- degree count part ----
        const int e = (blockIdx.x - GEMB) * 512 + threadIdx.x;
        if (e < TOT) {
            const int d = (e < EE) ? ei[EE + e] : (e - EE);
            pos[e] = (unsigned short)atomicAdd(deg + d, 1);
        }
        return;
    }

    // ---- gemm part ----
    const int r0   = blockIdx.x * RB;
    const int wv   = threadIdx.x >> 6;
    const int h    = wv >> 1;
    const int half = wv & 1;
    const int lane = threadIdx.x & 63;
    const int lrow = lane & 15;
    const int kg   = lane >> 4;
    const int n_base = h * 128 + half * 64;

    for (int i = threadIdx.x; i < RB * 32; i += 512) {
        const int row = i >> 5;
        const int c4  = (i & 31) * 4;
        const int grow = r0 + row;
        float4 v = make_float4(0.f, 0.f, 0.f, 0.f);
        if (grow < NN) v = *(const float4*)(x + (size_t)grow * CC + c4);
        uint2 o;
        o.x = f2bf(v.x) | (f2bf(v.y) << 16);
        o.y = f2bf(v.z) | (f2bf(v.w) << 16);
        *(uint2*)(&xs[row][c4]) = o;
    }

    s16x8 wf0[4], wf1[4], wf2[4], wf3[4];
#pragma unroll
    for (int kk = 0; kk < 4; ++kk) {
        wf0[kk] = *(const s16x8*)(wt + (size_t)(n_base + 0  + lrow) * CC + kg * 8 + kk * 32);
        wf1[kk] = *(const s16x8*)(wt + (size_t)(n_base + 16 + lrow) * CC + kg * 8 + kk * 32);
        wf2[kk] = *(const s16x8*)(wt + (size_t)(n_base + 32 + lrow) * CC + kg * 8 + kk * 32);
        wf3[kk] = *(const s16x8*)(wt + (size_t)(n_base + 48 + lrow) * CC + kg * 8 + kk * 32);
    }
    __syncthreads();

    const int cbase = h * CC + half * 64 + kg * 4;
    const float4 cs0 = *(const float4*)(att_s + cbase);
    const float4 cs1 = *(const float4*)(att_s + cbase + 16);
    const float4 cs2 = *(const float4*)(att_s + cbase + 32);
    const float4 cs3 = *(const float4*)(att_s + cbase + 48);
    const float4 cd0 = *(const float4*)(att_d + cbase);
    const float4 cd1 = *(const float4*)(att_d + cbase + 16);
    const float4 cd2 = *(const float4*)(att_d + cbase + 32);
    const float4 cd3 = *(const float4*)(att_d + cbase + 48);

    float psr[4], pdr[4];

#pragma unroll
    for (int rt = 0; rt < 4; ++rt) {
        f32x4 acc0 = {0.f, 0.f, 0.f, 0.f};
        f32x4 acc1 = {0.f, 0.f, 0.f, 0.f};
        f32x4 acc2 = {0.f, 0.f, 0.f, 0.f};
        f32x4 acc3 = {0.f, 0.f, 0.f, 0.f};
#pragma unroll
        for (int kk = 0; kk < 4; ++kk) {
            const s16x8 b = *(const s16x8*)(&xs[rt * 16 + lrow][kg * 8 + kk * 32]);
            acc0 = __builtin_amdgcn_mfma_f32_16x16x32_bf16(wf0[kk], b, acc0, 0, 0, 0);
            acc1 = __builtin_amdgcn_mfma_f32_16x16x32_bf16(wf1[kk], b, acc1, 0, 0, 0);
            acc2 = __builtin_amdgcn_mfma_f32_16x16x32_bf16(wf2[kk], b, acc2, 0, 0, 0);
            acc3 = __builtin_amdgcn_mfma_f32_16x16x32_bf16(wf3[kk], b, acc3, 0, 0, 0);
        }

        const int grow = r0 + rt * 16 + lrow;
        if (grow < NN) {
            unsigned char* orow = xhq + (size_t)grow * HCW + n_base + kg * 4;
            unsigned u;
            u = __builtin_amdgcn_cvt_pk_fp8_f32(acc0[0], acc0[1], 0u, false);
            u = __builtin_amdgcn_cvt_pk_fp8_f32(acc0[2], acc0[3], u, true);
            *(unsigned*)(orow) = u;
            u = __builtin_amdgcn_cvt_pk_fp8_f32(acc1[0], acc1[1], 0u, false);
            u = __builtin_amdgcn_cvt_pk_fp8_f32(acc1[2], acc1[3], u, true);
            *(unsigned*)(orow + 16) = u;
            u = __builtin_amdgcn_cvt_pk_fp8_f32(acc2[0], acc2[1], 0u, false);
            u = __builtin_amdgcn_cvt_pk_fp8_f32(acc2[2], acc2[3], u, true);
            *(unsigned*)(orow + 32) = u;
            u = __builtin_amdgcn_cvt_pk_fp8_f32(acc3[0], acc3[1], 0u, false);
            u = __builtin_amdgcn_cvt_pk_fp8_f32(acc3[2], acc3[3], u, true);
            *(unsigned*)(orow + 48) = u;
        }

        float ps = acc0[0]*cs0.x + acc0[1]*cs0.y + acc0[2]*cs0.z + acc0[3]*cs0.w
                 + acc1[0]*cs1.x + acc1[1]*cs1.y + acc1[2]*cs1.z + acc1[3]*cs1.w
                 + acc2[0]*cs2.x + acc2[1]*cs2.y + acc2[2]*cs2.z + acc2[3]*cs2.w
                 + acc3[0]*cs3.x + acc3[1]*cs3.y + acc3[2]*cs3.z + acc3[3]*cs3.w;
        float pd = acc0[0]*cd0.x + acc0[1]*cd0.y + acc0[2]*cd0.z + acc0[3]*cd0.w
                 + acc1[0]*cd1.x + acc1[1]*cd1.y + acc1[2]*cd1.z + acc1[3]*cd1.w
                 + acc2[0]*cd2.x + acc2[1]*cd2.y + acc2[2]*cd2.z + acc2[3]*cd2.w
                 + acc3[0]*cd3.x + acc3[1]*cd3.y + acc3[2]*cd3.z + acc3[3]*cd3.w;
        ps += __shfl_xor(ps, 16); ps += __shfl_xor(ps, 32);
        pd += __shfl_xor(pd, 16); pd += __shfl_xor(pd, 32);
        psr[rt] = ps;
        pdr[rt] = pd;
    }

#pragma unroll
    for (int rt = 0; rt < 4; ++rt) {
        red[wv][0][rt][lrow] = psr[rt];   // kg groups write identical values
        red[wv][1][rt][lrow] = pdr[rt];
    }
    __syncthreads();
    {
        const int t     = threadIdx.x & 15;
        const int rt    = (threadIdx.x >> 4) & 3;
        const int hh    = (threadIdx.x >> 6) & 3;
        const int which = threadIdx.x >> 8;          // 0 = src, 1 = dst
        const int row   = r0 + rt * 16 + t;
        if (row < NN) {
            const float v = red[hh * 2][which][rt][t] + red[hh * 2 + 1][which][rt][t];
            float* dst = which ? adst : asrc;
            dst[row * HH + hh] = v;
        }
    }
}

// -------- scan: per-block partial sums --------
__global__ __launch_bounds__(256) void s_part(
    const int* __restrict__ deg, int* __restrict__ part)
{
    const int idx = blockIdx.x * 256 + threadIdx.x;
    int v = (idx < NN) ? deg[idx] : 0;
#pragma unroll
    for (int off = 1; off < 64; off <<= 1) v += __shfl_xor(v, off);
    __shared__ int sm[4];
    if ((threadIdx.x & 63) == 0) sm[threadIdx.x >> 6] = v;
    __syncthreads();
    if (threadIdx.x == 0) part[blockIdx.x] = sm[0] + sm[1] + sm[2] + sm[3];
}

// -------- scan apply (mid-scan inlined) --------
__global__ __launch_bounds__(256) void s_apply(
    const int* __restrict__ deg, const int* __restrict__ part,
    int* __restrict__ rowptr)
{
    __shared__ int sm[256];
    __shared__ int ws[4];
    const int t   = threadIdx.x;
    const int bid = blockIdx.x;

    int pv = (t < SCAN_B && t < bid) ? part[t] : 0;
#pragma unroll
    for (int off = 1; off < 64; off <<= 1) pv += __shfl_xor(pv, off);
    if ((t & 63) == 0) ws[t >> 6] = pv;
    __syncthreads();
    const int poff = ws[0] + ws[1] + ws[2] + ws[3];

    const int idx = bid * 256 + t;
    const int v = (idx < NN) ? deg[idx] : 0;
    sm[t] = v;
    __syncthreads();
    for (int off = 1; off < 256; off <<= 1) {
        int u = (t >= off) ? sm[t - off] : 0;
        __syncthreads();
        sm[t] += u;
        __syncthreads();
    }
    if (idx < NN) rowptr[idx] = poff + sm[t] - v;   // exclusive
    if (bid == 0 && t == 0) rowptr[NN] = TOT;
}

// -------- K4: atomic-free scatter of src ids into dst-sorted CSR --------
__global__ __launch_bounds__(256) void k_scatter(
    const int* __restrict__ ei, const int* __restrict__ rowptr,
    const unsigned short* __restrict__ pos, int* __restrict__ csr_s)
{
    const int e = blockIdx.x * 256 + threadIdx.x;
    if (e >= TOT) return;
    int s, d;
    if (e < EE) { s = ei[e]; d = ei[EE + e]; } else { s = d = e - EE; }
    csr_s[rowptr[d] + pos[e]] = s;
}

// -------- K5: single-pass softmax + fp8 gather + residual, no tail loop ----
// one wave per node; lane = h*16 + t owns channels lane*8..+7 (8B per lane).
// Predicated 8-wide batches: idx clamped to end-1, weight zeroed when OOB.
__global__ __launch_bounds__(256) void k_gather(
    const int* __restrict__ rowptr, const int* __restrict__ csr_s,
    const float* __restrict__ asrc, const float* __restrict__ adst,
    const unsigned char* __restrict__ xhq, const float* __restrict__ x,
    const float* __restrict__ bias, float* __restrict__ out)
{
    const int gtid = blockIdx.x * 256 + threadIdx.x;
    const int n    = gtid >> 6;
    const int lane = threadIdx.x & 63;
    if (n >= NN) return;
    const int h = lane >> 4;
    const int t = lane & 15;

    const int beg = rowptr[n];
    const int end = rowptr[n + 1];
    const float ad = adst[n * HH + h];
    const uint2* xr = (const uint2*)xhq;    // 64 uint2 per 512B row

    float ssum = 0.f;
    float r0 = 0.f, r1 = 0.f, r2 = 0.f, r3 = 0.f;
    float r4 = 0.f, r5 = 0.f, r6 = 0.f, r7 = 0.f;

    for (int j = beg; j < end; j += 8) {
        int ss[8]; uint2 qq[8]; float ww[8];
#pragma unroll
        for (int u = 0; u < 8; ++u) {
            const int idx = (j + u < end) ? (j + u) : (end - 1);
            ss[u] = csr_s[idx];
        }
#pragma unroll
        for (int u = 0; u < 8; ++u) qq[u] = xr[(size_t)ss[u] * 64 + lane];
#pragma unroll
        for (int u = 0; u < 8; ++u) {
            float e = asrc[ss[u] * HH + h] + ad;
            e = e > 0.f ? e : 0.2f * e;
            float w = __expf(e);
            w = (j + u < end) ? w : 0.f;
            ww[u] = w;
            ssum += w;
        }
#pragma unroll
        for (int u = 0; u < 8; ++u) {
            const f32x2 p0 = __builtin_amdgcn_cvt_pk_f32_fp8(qq[u].x, false);
            const f32x2 p1 = __builtin_amdgcn_cvt_pk_f32_fp8(qq[u].x, true);
            const f32x2 p2 = __builtin_amdgcn_cvt_pk_f32_fp8(qq[u].y, false);
            const f32x2 p3 = __builtin_amdgcn_cvt_pk_f32_fp8(qq[u].y, true);
            const float w = ww[u];
            r0 += w * p0.x; r1 += w * p0.y;
            r2 += w * p1.x; r3 += w * p1.y;
            r4 += w * p2.x; r5 += w * p2.y;
            r6 += w * p3.x; r7 += w * p3.y;
        }
    }

    const float inv = 0.25f / (ssum + 1e-16f);
    r0 *= inv; r1 *= inv; r2 *= inv; r3 *= inv;
    r4 *= inv; r5 *= inv; r6 *= inv; r7 *= inv;

#pragma unroll
    for (int off = 16; off < 64; off <<= 1) {
        r0 += __shfl_xor(r0, off); r1 += __shfl_xor(r1, off);
        r2 += __shfl_xor(r2, off); r3 += __shfl_xor(r3, off);
        r4 += __shfl_xor(r4, off); r5 += __shfl_xor(r5, off);
        r6 += __shfl_xor(r6, off); r7 += __shfl_xor(r7, off);
    }

    if (h == 0) {
        const int c = t * 8;
        const float4 x0 = *(const float4*)(x + (size_t)n * CC + c);
        const float4 x1 = *(const float4*)(x + (size_t)n * CC + c + 4);
        const float4 b0 = *(const float4*)(bias + c);
        const float4 b1 = *(const float4*)(bias + c + 4);
        float4 o0, o1;
        o0.x = 0.8f * x0.x + 0.2f * (r0 + b0.x);
        o0.y = 0.8f * x0.y + 0.2f * (r1 + b0.y);
        o0.z = 0.8f * x0.z + 0.2f * (r2 + b0.z);
        o0.w = 0.8f * x0.w + 0.2f * (r3 + b0.w);
        o1.x = 0.8f * x1.x + 0.2f * (r4 + b1.x);
        o1.y = 0.8f * x1.y + 0.2f * (r5 + b1.y);
        o1.z = 0.8f * x1.z + 0.2f * (r6 + b1.z);
        o1.w = 0.8f * x1.w + 0.2f * (r7 + b1.w);
        *(float4*)(out + (size_t)n * CC + c)     = o0;
        *(float4*)(out + (size_t)n * CC + c + 4) = o1;
    }
}

extern "C" void kernel_launch(void* const* d_in, const int* in_sizes, int n_in,
                              void* d_out, int out_size, void* d_ws, size_t ws_size,
                              hipStream_t stream)
{
    const float* x     = (const float*)d_in[0];
    const int*   ei    = (const int*)d_in[1];
    const float* W     = (const float*)d_in[2];
    const float* att_s = (const float*)d_in[3];
    const float* att_d = (const float*)d_in[4];
    const float* bias  = (const float*)d_in[5];
    float* out = (float*)d_out;

    char* p = (char*)d_ws;
    unsigned char*  xhq   = (unsigned char*)p;  p += (size_t)NN * HCW;      // 25.6 MB
    unsigned short* wt    = (unsigned short*)p; p += (size_t)HCW * CC * 2;  // 128 KB
    float*          asrc  = (float*)p;          p += (size_t)NN * HH * 4;
    float*          adst  = (float*)p;          p += (size_t)NN * HH * 4;
    int*            deg   = (int*)p;            p += (size_t)NN * 4;        // zeroed
    unsigned short* pos   = (unsigned short*)p; p += (size_t)TOT * 2;
    int*            rowptr= (int*)p;            p += (size_t)(NN + 1) * 4;
    int*            csr_s = (int*)p;            p += (size_t)TOT * 4;
    int*            part  = (int*)p;            p += (size_t)SCAN_B * 4;

    hipMemsetAsync(deg, 0, (size_t)NN * 4, stream);

    k_prep_w<<<(HCW * CC + 255) / 256, 256, 0, stream>>>(W, wt);
    k_fat<<<GEMB + CNTB, 512, 0, stream>>>(x, wt, att_s, att_d, ei, xhq, asrc, adst, deg, pos);
    s_part<<<SCAN_B, 256, 0, stream>>>(deg, part);
    s_apply<<<SCAN_B, 256, 0, stream>>>(deg, part, rowptr);
    k_scatter<<<(TOT + 255) / 256, 256, 0, stream>>>(ei, rowptr, pos, csr_s);
    {
        const long long threads = (long long)NN * 64;
        const int blocks = (int)((threads + 255) / 256);
        k_gather<<<blocks, 256, 0, stream>>>(rowptr, csr_s, asrc, adst, xhq, x, bias, out);
    }
}

// Round 11
// 166.228 us; speedup vs baseline: 1.0840x; 1.0840x over previous
//
#include <hip/hip_runtime.h>
#include <math.h>

#define NN 50000
#define EE 800000
#define TOT (EE + NN)          // 850000 edges incl. self loops
#define CC 128
#define HH 4
#define HCW 512                // H*C
#define SCAN_B 196             // ceil(NN/256)
#define RB 64                  // rows per gemm block
#define GEMB ((NN + RB - 1) / RB)        // 782 gemm blocks
#define CNTB ((TOT + 511) / 512)         // 1661 count blocks

typedef short s16x8 __attribute__((ext_vector_type(8)));
typedef float f32x4 __attribute__((ext_vector_type(4)));
typedef float f32x2 __attribute__((ext_vector_type(2)));

// fp32 -> bf16 bits, round-to-nearest-even
__device__ __forceinline__ unsigned f2bf(float f) {
    unsigned u = __float_as_uint(f);
    return (u + 0x7fffu + ((u >> 16) & 1u)) >> 16;
}

// -------- P2: W [128][512] fp32 -> Wt [512][128] bf16 --------
__global__ __launch_bounds__(256) void k_prep_w(
    const float* __restrict__ W, unsigned short* __restrict__ wt)
{
    const int i = blockIdx.x * 256 + threadIdx.x;   // i = c*128 + k
    if (i >= HCW * CC) return;
    const int c = i >> 7, k = i & 127;
    wt[i] = (unsigned short)f2bf(W[(size_t)k * HCW + c]);
}

// -------- K1 (fat): blocks [0,GEMB) = MFMA gemm -> fp8 xh + fused att;
//                    blocks [GEMB, GEMB+CNTB) = degree count --------
// NOTE: r9 epilogue kept verbatim — r10's hoisted att coeffs + psr/pdr arrays
// blew the 64-VGPR budget (spills: MfmaUtil 2.8%, occ 38%, +40us).
__global__ __launch_bounds__(512, 4) void k_fat(
    const float* __restrict__ x,             // [NN][128] fp32
    const unsigned short* __restrict__ wt,   // [512][128] bf16 = W^T
    const float* __restrict__ att_s, const float* __restrict__ att_d,
    const int* __restrict__ ei,
    unsigned char* __restrict__ xhq,         // [NN][512] fp8 e4m3
    float* __restrict__ asrc, float* __restrict__ adst,
    int* __restrict__ deg, unsigned short* __restrict__ pos)
{
    __shared__ unsigned short xs[RB][CC + 8];   // 64x136 bf16
    __shared__ float red[8][2][16];

    if (blockIdx.x >= GEMB) {
        // ---- degree count part ----
        const int e = (blockIdx.x - GEMB) * 512 + threadIdx.x;
        if (e < TOT) {
            const int d = (e < EE) ? ei[EE + e] : (e - EE);
            pos[e] = (unsigned short)atomicAdd(deg + d, 1);
        }
        return;
    }

    // ---- gemm part ----
    const int r0   = blockIdx.x * RB;
    const int wv   = threadIdx.x >> 6;
    const int h    = wv >> 1;
    const int half = wv & 1;
    const int lane = threadIdx.x & 63;
    const int lrow = lane & 15;
    const int kg   = lane >> 4;
    const int n_base = h * 128 + half * 64;

    for (int i = threadIdx.x; i < RB * 32; i += 512) {
        const int row = i >> 5;
        const int c4  = (i & 31) * 4;
        const int grow = r0 + row;
        float4 v = make_float4(0.f, 0.f, 0.f, 0.f);
        if (grow < NN) v = *(const float4*)(x + (size_t)grow * CC + c4);
        uint2 o;
        o.x = f2bf(v.x) | (f2bf(v.y) << 16);
        o.y = f2bf(v.z) | (f2bf(v.w) << 16);
        *(uint2*)(&xs[row][c4]) = o;
    }

    s16x8 wf0[4], wf1[4], wf2[4], wf3[4];
#pragma unroll
    for (int kk = 0; kk < 4; ++kk) {
        wf0[kk] = *(const s16x8*)(wt + (size_t)(n_base + 0  + lrow) * CC + kg * 8 + kk * 32);
        wf1[kk] = *(const s16x8*)(wt + (size_t)(n_base + 16 + lrow) * CC + kg * 8 + kk * 32);
        wf2[kk] = *(const s16x8*)(wt + (size_t)(n_base + 32 + lrow) * CC + kg * 8 + kk * 32);
        wf3[kk] = *(const s16x8*)(wt + (size_t)(n_base + 48 + lrow) * CC + kg * 8 + kk * 32);
    }
    __syncthreads();

    const int cbase = h * CC + half * 64 + kg * 4;

    for (int rt = 0; rt < 4; ++rt) {
        f32x4 acc0 = {0.f, 0.f, 0.f, 0.f};
        f32x4 acc1 = {0.f, 0.f, 0.f, 0.f};
        f32x4 acc2 = {0.f, 0.f, 0.f, 0.f};
        f32x4 acc3 = {0.f, 0.f, 0.f, 0.f};
#pragma unroll
        for (int kk = 0; kk < 4; ++kk) {
            const s16x8 b = *(const s16x8*)(&xs[rt * 16 + lrow][kg * 8 + kk * 32]);
            acc0 = __builtin_amdgcn_mfma_f32_16x16x32_bf16(wf0[kk], b, acc0, 0, 0, 0);
            acc1 = __builtin_amdgcn_mfma_f32_16x16x32_bf16(wf1[kk], b, acc1, 0, 0, 0);
            acc2 = __builtin_amdgcn_mfma_f32_16x16x32_bf16(wf2[kk], b, acc2, 0, 0, 0);
            acc3 = __builtin_amdgcn_mfma_f32_16x16x32_bf16(wf3[kk], b, acc3, 0, 0, 0);
        }

        const int grow = r0 + rt * 16 + lrow;
        if (grow < NN) {
            // pack each 4-channel fragment into 4 fp8 bytes (one dword)
            unsigned char* orow = xhq + (size_t)grow * HCW + n_base + kg * 4;
            unsigned u;
            u = __builtin_amdgcn_cvt_pk_fp8_f32(acc0[0], acc0[1], 0u, false);
            u = __builtin_amdgcn_cvt_pk_fp8_f32(acc0[2], acc0[3], u, true);
            *(unsigned*)(orow) = u;
            u = __builtin_amdgcn_cvt_pk_fp8_f32(acc1[0], acc1[1], 0u, false);
            u = __builtin_amdgcn_cvt_pk_fp8_f32(acc1[2], acc1[3], u, true);
            *(unsigned*)(orow + 16) = u;
            u = __builtin_amdgcn_cvt_pk_fp8_f32(acc2[0], acc2[1], 0u, false);
            u = __builtin_amdgcn_cvt_pk_fp8_f32(acc2[2], acc2[3], u, true);
            *(unsigned*)(orow + 32) = u;
            u = __builtin_amdgcn_cvt_pk_fp8_f32(acc3[0], acc3[1], 0u, false);
            u = __builtin_amdgcn_cvt_pk_fp8_f32(acc3[2], acc3[3], u, true);
            *(unsigned*)(orow + 48) = u;
        }

        float ps, pd;
        {
            const float4 c0 = *(const float4*)(att_s + cbase);
            const float4 c1 = *(const float4*)(att_s + cbase + 16);
            const float4 c2 = *(const float4*)(att_s + cbase + 32);
            const float4 c3 = *(const float4*)(att_s + cbase + 48);
            ps = acc0[0]*c0.x + acc0[1]*c0.y + acc0[2]*c0.z + acc0[3]*c0.w
               + acc1[0]*c1.x + acc1[1]*c1.y + acc1[2]*c1.z + acc1[3]*c1.w
               + acc2[0]*c2.x + acc2[1]*c2.y + acc2[2]*c2.z + acc2[3]*c2.w
               + acc3[0]*c3.x + acc3[1]*c3.y + acc3[2]*c3.z + acc3[3]*c3.w;
        }
        {
            const float4 c0 = *(const float4*)(att_d + cbase);
            const float4 c1 = *(const float4*)(att_d + cbase + 16);
            const float4 c2 = *(const float4*)(att_d + cbase + 32);
            const float4 c3 = *(const float4*)(att_d + cbase + 48);
            pd = acc0[0]*c0.x + acc0[1]*c0.y + acc0[2]*c0.z + acc0[3]*c0.w
               + acc1[0]*c1.x + acc1[1]*c1.y + acc1[2]*c1.z + acc1[3]*c1.w
               + acc2[0]*c2.x + acc2[1]*c2.y + acc2[2]*c2.z + acc2[3]*c2.w
               + acc3[0]*c3.x + acc3[1]*c3.y + acc3[2]*c3.z + acc3[3]*c3.w;
        }
        ps += __shfl_xor(ps, 16); ps += __shfl_xor(ps, 32);
        pd += __shfl_xor(pd, 16); pd += __shfl_xor(pd, 32);
        red[wv][0][lrow] = ps;
        red[wv][1][lrow] = pd;
        __syncthreads();
        if (threadIdx.x < 128) {
            const int t     = threadIdx.x & 15;
            const int hh    = (threadIdx.x >> 4) & 3;
            const int which = threadIdx.x >> 6;
            const int row   = r0 + rt * 16 + t;
            if (row < NN) {
                const float v = red[hh * 2][which][t] + red[hh * 2 + 1][which][t];
                float* dst = which ? adst : asrc;
                dst[row * HH + hh] = v;
            }
        }
        __syncthreads();
    }
}

// -------- scan: per-block partial sums --------
__global__ __launch_bounds__(256) void s_part(
    const int* __restrict__ deg, int* __restrict__ part)
{
    const int idx = blockIdx.x * 256 + threadIdx.x;
    int v = (idx < NN) ? deg[idx] : 0;
#pragma unroll
    for (int off = 1; off < 64; off <<= 1) v += __shfl_xor(v, off);
    __shared__ int sm[4];
    if ((threadIdx.x & 63) == 0) sm[threadIdx.x >> 6] = v;
    __syncthreads();
    if (threadIdx.x == 0) part[blockIdx.x] = sm[0] + sm[1] + sm[2] + sm[3];
}

// -------- scan apply (mid-scan inlined) --------
__global__ __launch_bounds__(256) void s_apply(
    const int* __restrict__ deg, const int* __restrict__ part,
    int* __restrict__ rowptr)
{
    __shared__ int sm[256];
    __shared__ int ws[4];
    const int t   = threadIdx.x;
    const int bid = blockIdx.x;

    int pv = (t < SCAN_B && t < bid) ? part[t] : 0;
#pragma unroll
    for (int off = 1; off < 64; off <<= 1) pv += __shfl_xor(pv, off);
    if ((t & 63) == 0) ws[t >> 6] = pv;
    __syncthreads();
    const int poff = ws[0] + ws[1] + ws[2] + ws[3];

    const int idx = bid * 256 + t;
    const int v = (idx < NN) ? deg[idx] : 0;
    sm[t] = v;
    __syncthreads();
    for (int off = 1; off < 256; off <<= 1) {
        int u = (t >= off) ? sm[t - off] : 0;
        __syncthreads();
        sm[t] += u;
        __syncthreads();
    }
    if (idx < NN) rowptr[idx] = poff + sm[t] - v;   // exclusive
    if (bid == 0 && t == 0) rowptr[NN] = TOT;
}

// -------- K4: atomic-free scatter of src ids into dst-sorted CSR --------
__global__ __launch_bounds__(256) void k_scatter(
    const int* __restrict__ ei, const int* __restrict__ rowptr,
    const unsigned short* __restrict__ pos, int* __restrict__ csr_s)
{
    const int e = blockIdx.x * 256 + threadIdx.x;
    if (e >= TOT) return;
    int s, d;
    if (e < EE) { s = ei[e]; d = ei[EE + e]; } else { s = d = e - EE; }
    csr_s[rowptr[d] + pos[e]] = s;
}

// -------- K5: single-pass softmax + fp8 gather + residual, no tail loop ----
// one wave per node; lane = h*16 + t owns channels lane*8..+7 (8B per lane).
// Predicated 8-wide batches: idx clamped to end-1, weight zeroed when OOB.
__global__ __launch_bounds__(256) void k_gather(
    const int* __restrict__ rowptr, const int* __restrict__ csr_s,
    const float* __restrict__ asrc, const float* __restrict__ adst,
    const unsigned char* __restrict__ xhq, const float* __restrict__ x,
    const float* __restrict__ bias, float* __restrict__ out)
{
    const int gtid = blockIdx.x * 256 + threadIdx.x;
    const int n    = gtid >> 6;
    const int lane = threadIdx.x & 63;
    if (n >= NN) return;
    const int h = lane >> 4;
    const int t = lane & 15;

    const int beg = rowptr[n];
    const int end = rowptr[n + 1];
    const float ad = adst[n * HH + h];
    const uint2* xr = (const uint2*)xhq;    // 64 uint2 per 512B row

    float ssum = 0.f;
    float r0 = 0.f, r1 = 0.f, r2 = 0.f, r3 = 0.f;
    float r4 = 0.f, r5 = 0.f, r6 = 0.f, r7 = 0.f;

    for (int j = beg; j < end; j += 8) {
        int ss[8]; uint2 qq[8]; float ww[8];
#pragma unroll
        for (int u = 0; u < 8; ++u) {
            const int idx = (j + u < end) ? (j + u) : (end - 1);
            ss[u] = csr_s[idx];
        }
#pragma unroll
        for (int u = 0; u < 8; ++u) qq[u] = xr[(size_t)ss[u] * 64 + lane];
#pragma unroll
        for (int u = 0; u < 8; ++u) {
            float e = asrc[ss[u] * HH + h] + ad;
            e = e > 0.f ? e : 0.2f * e;
            float w = __expf(e);
            w = (j + u < end) ? w : 0.f;
            ww[u] = w;
            ssum += w;
        }
#pragma unroll
        for (int u = 0; u < 8; ++u) {
            const f32x2 p0 = __builtin_amdgcn_cvt_pk_f32_fp8(qq[u].x, false);
            const f32x2 p1 = __builtin_amdgcn_cvt_pk_f32_fp8(qq[u].x, true);
            const f32x2 p2 = __builtin_amdgcn_cvt_pk_f32_fp8(qq[u].y, false);
            const f32x2 p3 = __builtin_amdgcn_cvt_pk_f32_fp8(qq[u].y, true);
            const float w = ww[u];
            r0 += w * p0.x; r1 += w * p0.y;
            r2 += w * p1.x; r3 += w * p1.y;
            r4 += w * p2.x; r5 += w * p2.y;
            r6 += w * p3.x; r7 += w * p3.y;
        }
    }

    const float inv = 0.25f / (ssum + 1e-16f);
    r0 *= inv; r1 *= inv; r2 *= inv; r3 *= inv;
    r4 *= inv; r5 *= inv; r6 *= inv; r7 *= inv;

#pragma unroll
    for (int off = 16; off < 64; off <<= 1) {
        r0 += __shfl_xor(r0, off); r1 += __shfl_xor(r1, off);
        r2 += __shfl_xor(r2, off); r3 += __shfl_xor(r3, off);
        r4 += __shfl_xor(r4, off); r5 += __shfl_xor(r5, off);
        r6 += __shfl_xor(r6, off); r7 += __shfl_xor(r7, off);
    }

    if (h == 0) {
        const int c = t * 8;
        const float4 x0 = *(const float4*)(x + (size_t)n * CC + c);
        const float4 x1 = *(const float4*)(x + (size_t)n * CC + c + 4);
        const float4 b0 = *(const float4*)(bias + c);
        const float4 b1 = *(const float4*)(bias + c + 4);
        float4 o0, o1;
        o0.x = 0.8f * x0.x + 0.2f * (r0 + b0.x);
        o0.y = 0.8f * x0.y + 0.2f * (r1 + b0.y);
        o0.z = 0.8f * x0.z + 0.2f * (r2 + b0.z);
        o0.w = 0.8f * x0.w + 0.2f * (r3 + b0.w);
        o1.x = 0.8f * x1.x + 0.2f * (r4 + b1.x);
        o1.y = 0.8f * x1.y + 0.2f * (r5 + b1.y);
        o1.z = 0.8f * x1.z + 0.2f * (r6 + b1.z);
        o1.w = 0.8f * x1.w + 0.2f * (r7 + b1.w);
        *(float4*)(out + (size_t)n * CC + c)     = o0;
        *(float4*)(out + (size_t)n * CC + c + 4) = o1;
    }
}

extern "C" void kernel_launch(void* const* d_in, const int* in_sizes, int n_in,
                              void* d_out, int out_size, void* d_ws, size_t ws_size,
                              hipStream_t stream)
{
    const float* x     = (const float*)d_in[0];
    const int*   ei    = (const int*)d_in[1];
    const float* W     = (const float*)d_in[2];
    const float* att_s = (const float*)d_in[3];
    const float* att_d = (const float*)d_in[4];
    const float* bias  = (const float*)d_in[5];
    float* out = (float*)d_out;

    char* p = (char*)d_ws;
    unsigned char*  xhq   = (unsigned char*)p;  p += (size_t)NN * HCW;      // 25.6 MB
    unsigned short* wt    = (unsigned short*)p; p += (size_t)HCW * CC * 2;  // 128 KB
    float*          asrc  = (float*)p;          p += (size_t)NN * HH * 4;
    float*          adst  = (float*)p;          p += (size_t)NN * HH * 4;
    int*            deg   = (int*)p;            p += (size_t)NN * 4;        // zeroed
    unsigned short* pos   = (unsigned short*)p; p += (size_t)TOT * 2;
    int*            rowptr= (int*)p;            p += (size_t)(NN + 1) * 4;
    int*            csr_s = (int*)p;            p += (size_t)TOT * 4;
    int*            part  = (int*)p;            p += (size_t)SCAN_B * 4;

    hipMemsetAsync(deg, 0, (size_t)NN * 4, stream);

    k_prep_w<<<(HCW * CC + 255) / 256, 256, 0, stream>>>(W, wt);
    k_fat<<<GEMB + CNTB, 512, 0, stream>>>(x, wt, att_s, att_d, ei, xhq, asrc, adst, deg, pos);
    s_part<<<SCAN_B, 256, 0, stream>>>(deg, part);
    s_apply<<<SCAN_B, 256, 0, stream>>>(deg, part, rowptr);
    k_scatter<<<(TOT + 255) / 256, 256, 0, stream>>>(ei, rowptr, pos, csr_s);
    {
        const long long threads = (long long)NN * 64;
        const int blocks = (int)((threads + 255) / 256);
        k_gather<<<blocks, 256, 0, stream>>>(rowptr, csr_s, asrc, adst, xhq, x, bias, out);
    }
}

// Round 12
// 162.641 us; speedup vs baseline: 1.1079x; 1.0221x over previous
//
#include <hip/hip_runtime.h>
#include <math.h>

#define NN 50000
#define EE 800000
#define TOT (EE + NN)          // 850000 edges incl. self loops
#define CC 128
#define HH 4
#define HCW 512                // H*C
#define SCAN_B 196             // ceil(NN/256)
#define RB 64                  // rows per gemm block
#define GEMB ((NN + RB - 1) / RB)        // 782 gemm blocks
#define CNTB ((TOT + 511) / 512)         // 1661 count blocks
#define LOG2E 1.442695040888963f

typedef short s16x8 __attribute__((ext_vector_type(8)));
typedef float f32x4 __attribute__((ext_vector_type(4)));
typedef float f32x2 __attribute__((ext_vector_type(2)));

// fp32 -> bf16 bits, round-to-nearest-even
__device__ __forceinline__ unsigned f2bf(float f) {
    unsigned u = __float_as_uint(f);
    return (u + 0x7fffu + ((u >> 16) & 1u)) >> 16;
}

// -------- P2: W [128][512] fp32 -> Wt [512][128] bf16 --------
__global__ __launch_bounds__(256) void k_prep_w(
    const float* __restrict__ W, unsigned short* __restrict__ wt)
{
    const int i = blockIdx.x * 256 + threadIdx.x;   // i = c*128 + k
    if (i >= HCW * CC) return;
    const int c = i >> 7, k = i & 127;
    wt[i] = (unsigned short)f2bf(W[(size_t)k * HCW + c]);
}

// -------- K1 (fat): blocks [0,GEMB) = MFMA gemm -> fp8 xh + fused att;
//                    blocks [GEMB, GEMB+CNTB) = degree count --------
// NOTE: epilogue kept in r9/r11 shape — hoisting att coeffs spills (r10).
// asrc/adst are stored pre-scaled by log2(e) so the gather uses exp2 directly.
__global__ __launch_bounds__(512, 4) void k_fat(
    const float* __restrict__ x,             // [NN][128] fp32
    const unsigned short* __restrict__ wt,   // [512][128] bf16 = W^T
    const float* __restrict__ att_s, const float* __restrict__ att_d,
    const int* __restrict__ ei,
    unsigned char* __restrict__ xhq,         // [NN][512] fp8 e4m3
    float* __restrict__ asrc, float* __restrict__ adst,
    int* __restrict__ deg, unsigned short* __restrict__ pos)
{
    __shared__ unsigned short xs[RB][CC + 8];   // 64x136 bf16
    __shared__ float red[8][2][16];

    if (blockIdx.x >= GEMB) {
        // ---- degree count part ----
        const int e = (blockIdx.x - GEMB) * 512 + threadIdx.x;
        if (e < TOT) {
            const int d = (e < EE) ? ei[EE + e] : (e - EE);
            pos[e] = (unsigned short)atomicAdd(deg + d, 1);
        }
        return;
    }

    // ---- gemm part ----
    const int r0   = blockIdx.x * RB;
    const int wv   = threadIdx.x >> 6;
    const int h    = wv >> 1;
    const int half = wv & 1;
    const int lane = threadIdx.x & 63;
    const int lrow = lane & 15;
    const int kg   = lane >> 4;
    const int n_base = h * 128 + half * 64;

    for (int i = threadIdx.x; i < RB * 32; i += 512) {
        const int row = i >> 5;
        const int c4  = (i & 31) * 4;
        const int grow = r0 + row;
        float4 v = make_float4(0.f, 0.f, 0.f, 0.f);
        if (grow < NN) v = *(const float4*)(x + (size_t)grow * CC + c4);
        uint2 o;
        o.x = f2bf(v.x) | (f2bf(v.y) << 16);
        o.y = f2bf(v.z) | (f2bf(v.w) << 16);
        *(uint2*)(&xs[row][c4]) = o;
    }

    s16x8 wf0[4], wf1[4], wf2[4], wf3[4];
#pragma unroll
    for (int kk = 0; kk < 4; ++kk) {
        wf0[kk] = *(const s16x8*)(wt + (size_t)(n_base + 0  + lrow) * CC + kg * 8 + kk * 32);
        wf1[kk] = *(const s16x8*)(wt + (size_t)(n_base + 16 + lrow) * CC + kg * 8 + kk * 32);
        wf2[kk] = *(const s16x8*)(wt + (size_t)(n_base + 32 + lrow) * CC + kg * 8 + kk * 32);
        wf3[kk] = *(const s16x8*)(wt + (size_t)(n_base + 48 + lrow) * CC + kg * 8 + kk * 32);
    }
    __syncthreads();

    const int cbase = h * CC + half * 64 + kg * 4;

    for (int rt = 0; rt < 4; ++rt) {
        f32x4 acc0 = {0.f, 0.f, 0.f, 0.f};
        f32x4 acc1 = {0.f, 0.f, 0.f, 0.f};
        f32x4 acc2 = {0.f, 0.f, 0.f, 0.f};
        f32x4 acc3 = {0.f, 0.f, 0.f, 0.f};
#pragma unroll
        for (int kk = 0; kk < 4; ++kk) {
            const s16x8 b = *(const s16x8*)(&xs[rt * 16 + lrow][kg * 8 + kk * 32]);
            acc0 = __builtin_amdgcn_mfma_f32_16x16x32_bf16(wf0[kk], b, acc0, 0, 0, 0);
            acc1 = __builtin_amdgcn_mfma_f32_16x16x32_bf16(wf1[kk], b, acc1, 0, 0, 0);
            acc2 = __builtin_amdgcn_mfma_f32_16x16x32_bf16(wf2[kk], b, acc2, 0, 0, 0);
            acc3 = __builtin_amdgcn_mfma_f32_16x16x32_bf16(wf3[kk], b, acc3, 0, 0, 0);
        }

        const int grow = r0 + rt * 16 + lrow;
        if (grow < NN) {
            // pack each 4-channel fragment into 4 fp8 bytes (one dword)
            unsigned char* orow = xhq + (size_t)grow * HCW + n_base + kg * 4;
            unsigned u;
            u = __builtin_amdgcn_cvt_pk_fp8_f32(acc0[0], acc0[1], 0u, false);
            u = __builtin_amdgcn_cvt_pk_fp8_f32(acc0[2], acc0[3], u, true);
            *(unsigned*)(orow) = u;
            u = __builtin_amdgcn_cvt_pk_fp8_f32(acc1[0], acc1[1], 0u, false);
            u = __builtin_amdgcn_cvt_pk_fp8_f32(acc1[2], acc1[3], u, true);
            *(unsigned*)(orow + 16) = u;
            u = __builtin_amdgcn_cvt_pk_fp8_f32(acc2[0], acc2[1], 0u, false);
            u = __builtin_amdgcn_cvt_pk_fp8_f32(acc2[2], acc2[3], u, true);
            *(unsigned*)(orow + 32) = u;
            u = __builtin_amdgcn_cvt_pk_fp8_f32(acc3[0], acc3[1], 0u, false);
            u = __builtin_amdgcn_cvt_pk_fp8_f32(acc3[2], acc3[3], u, true);
            *(unsigned*)(orow + 48) = u;
        }

        float ps, pd;
        {
            const float4 c0 = *(const float4*)(att_s + cbase);
            const float4 c1 = *(const float4*)(att_s + cbase + 16);
            const float4 c2 = *(const float4*)(att_s + cbase + 32);
            const float4 c3 = *(const float4*)(att_s + cbase + 48);
            ps = acc0[0]*c0.x + acc0[1]*c0.y + acc0[2]*c0.z + acc0[3]*c0.w
               + acc1[0]*c1.x + acc1[1]*c1.y + acc1[2]*c1.z + acc1[3]*c1.w
               + acc2[0]*c2.x + acc2[1]*c2.y + acc2[2]*c2.z + acc2[3]*c2.w
               + acc3[0]*c3.x + acc3[1]*c3.y + acc3[2]*c3.z + acc3[3]*c3.w;
        }
        {
            const float4 c0 = *(const float4*)(att_d + cbase);
            const float4 c1 = *(const float4*)(att_d + cbase + 16);
            const float4 c2 = *(const float4*)(att_d + cbase + 32);
            const float4 c3 = *(const float4*)(att_d + cbase + 48);
            pd = acc0[0]*c0.x + acc0[1]*c0.y + acc0[2]*c0.z + acc0[3]*c0.w
               + acc1[0]*c1.x + acc1[1]*c1.y + acc1[2]*c1.z + acc1[3]*c1.w
               + acc2[0]*c2.x + acc2[1]*c2.y + acc2[2]*c2.z + acc2[3]*c2.w
               + acc3[0]*c3.x + acc3[1]*c3.y + acc3[2]*c3.z + acc3[3]*c3.w;
        }
        ps += __shfl_xor(ps, 16); ps += __shfl_xor(ps, 32);
        pd += __shfl_xor(pd, 16); pd += __shfl_xor(pd, 32);
        red[wv][0][lrow] = ps;
        red[wv][1][lrow] = pd;
        __syncthreads();
        if (threadIdx.x < 128) {
            const int t     = threadIdx.x & 15;
            const int hh    = (threadIdx.x >> 4) & 3;
            const int which = threadIdx.x >> 6;
            const int row   = r0 + rt * 16 + t;
            if (row < NN) {
                const float v = red[hh * 2][which][t] + red[hh * 2 + 1][which][t];
                float* dst = which ? adst : asrc;
                dst[row * HH + hh] = v * LOG2E;   // pre-scale for exp2 in gather
            }
        }
        __syncthreads();
    }
}

// -------- scan: per-block partial sums --------
__global__ __launch_bounds__(256) void s_part(
    const int* __restrict__ deg, int* __restrict__ part)
{
    const int idx = blockIdx.x * 256 + threadIdx.x;
    int v = (idx < NN) ? deg[idx] : 0;
#pragma unroll
    for (int off = 1; off < 64; off <<= 1) v += __shfl_xor(v, off);
    __shared__ int sm[4];
    if ((threadIdx.x & 63) == 0) sm[threadIdx.x >> 6] = v;
    __syncthreads();
    if (threadIdx.x == 0) part[blockIdx.x] = sm[0] + sm[1] + sm[2] + sm[3];
}

// -------- scan apply (mid-scan inlined) --------
__global__ __launch_bounds__(256) void s_apply(
    const int* __restrict__ deg, const int* __restrict__ part,
    int* __restrict__ rowptr)
{
    __shared__ int sm[256];
    __shared__ int ws[4];
    const int t   = threadIdx.x;
    const int bid = blockIdx.x;

    int pv = (t < SCAN_B && t < bid) ? part[t] : 0;
#pragma unroll
    for (int off = 1; off < 64; off <<= 1) pv += __shfl_xor(pv, off);
    if ((t & 63) == 0) ws[t >> 6] = pv;
    __syncthreads();
    const int poff = ws[0] + ws[1] + ws[2] + ws[3];

    const int idx = bid * 256 + t;
    const int v = (idx < NN) ? deg[idx] : 0;
    sm[t] = v;
    __syncthreads();
    for (int off = 1; off < 256; off <<= 1) {
        int u = (t >= off) ? sm[t - off] : 0;
        __syncthreads();
        sm[t] += u;
        __syncthreads();
    }
    if (idx < NN) rowptr[idx] = poff + sm[t] - v;   // exclusive
    if (bid == 0 && t == 0) rowptr[NN] = TOT;
}

// -------- K4: atomic-free scatter of src ids into dst-sorted CSR --------
__global__ __launch_bounds__(256) void k_scatter(
    const int* __restrict__ ei, const int* __restrict__ rowptr,
    const unsigned short* __restrict__ pos, int* __restrict__ csr_s)
{
    const int e = blockIdx.x * 256 + threadIdx.x;
    if (e >= TOT) return;
    int s, d;
    if (e < EE) { s = ei[e]; d = ei[EE + e]; } else { s = d = e - EE; }
    csr_s[rowptr[d] + pos[e]] = s;
}

// -------- K5: single-pass softmax + fp8 gather + residual --------
// one wave per node; lane = h*16 + t owns channels lane*8..+7.
// Main loop: exact batch-8 (no predication). Tail: <=2 predicated batch-4s.
// asrc/adst pre-scaled by log2(e): w = exp2(score).
__global__ __launch_bounds__(256) void k_gather(
    const int* __restrict__ rowptr, const int* __restrict__ csr_s,
    const float* __restrict__ asrc, const float* __restrict__ adst,
    const unsigned char* __restrict__ xhq, const float* __restrict__ x,
    const float* __restrict__ bias, float* __restrict__ out)
{
    const int gtid = blockIdx.x * 256 + threadIdx.x;
    const int n    = gtid >> 6;
    const int lane = threadIdx.x & 63;
    if (n >= NN) return;
    const int h = lane >> 4;
    const int t = lane & 15;

    const int beg = rowptr[n];
    const int end = rowptr[n + 1];
    const float ad = adst[n * HH + h];
    const uint2* xr = (const uint2*)xhq;    // 64 uint2 per 512B row

    float ssum = 0.f;
    float r0 = 0.f, r1 = 0.f, r2 = 0.f, r3 = 0.f;
    float r4 = 0.f, r5 = 0.f, r6 = 0.f, r7 = 0.f;

    int j = beg;
    // ---- exact 8-wide batches, no predication ----
    for (; j + 8 <= end; j += 8) {
        int ss[8]; uint2 qq[8]; float ww[8];
#pragma unroll
        for (int u = 0; u < 8; ++u) ss[u] = csr_s[j + u];
#pragma unroll
        for (int u = 0; u < 8; ++u) qq[u] = xr[((size_t)ss[u] << 6) + lane];
#pragma unroll
        for (int u = 0; u < 8; ++u) {
            float e = asrc[ss[u] * HH + h] + ad;
            e = e > 0.f ? e : 0.2f * e;
            ww[u] = exp2f(e);
            ssum += ww[u];
        }
#pragma unroll
        for (int u = 0; u < 8; ++u) {
            const f32x2 p0 = __builtin_amdgcn_cvt_pk_f32_fp8(qq[u].x, false);
            const f32x2 p1 = __builtin_amdgcn_cvt_pk_f32_fp8(qq[u].x, true);
            const f32x2 p2 = __builtin_amdgcn_cvt_pk_f32_fp8(qq[u].y, false);
            const f32x2 p3 = __builtin_amdgcn_cvt_pk_f32_fp8(qq[u].y, true);
            const float w = ww[u];
            r0 += w * p0.x; r1 += w * p0.y;
            r2 += w * p1.x; r3 += w * p1.y;
            r4 += w * p2.x; r5 += w * p2.y;
            r6 += w * p3.x; r7 += w * p3.y;
        }
    }
    // ---- tail: up to two predicated 4-wide batches ----
    for (int base = j; base < end; base += 4) {
        int ss[4]; uint2 qq[4]; float ww[4];
#pragma unroll
        for (int u = 0; u < 4; ++u) {
            const int idx = (base + u < end) ? (base + u) : (end - 1);
            ss[u] = csr_s[idx];
        }
#pragma unroll
        for (int u = 0; u < 4; ++u) qq[u] = xr[((size_t)ss[u] << 6) + lane];
#pragma unroll
        for (int u = 0; u < 4; ++u) {
            float e = asrc[ss[u] * HH + h] + ad;
            e = e > 0.f ? e : 0.2f * e;
            float w = exp2f(e);
            w = (base + u < end) ? w : 0.f;
            ww[u] = w;
            ssum += w;
        }
#pragma unroll
        for (int u = 0; u < 4; ++u) {
            const f32x2 p0 = __builtin_amdgcn_cvt_pk_f32_fp8(qq[u].x, false);
            const f32x2 p1 = __builtin_amdgcn_cvt_pk_f32_fp8(qq[u].x, true);
            const f32x2 p2 = __builtin_amdgcn_cvt_pk_f32_fp8(qq[u].y, false);
            const f32x2 p3 = __builtin_amdgcn_cvt_pk_f32_fp8(qq[u].y, true);
            const float w = ww[u];
            r0 += w * p0.x; r1 += w * p0.y;
            r2 += w * p1.x; r3 += w * p1.y;
            r4 += w * p2.x; r5 += w * p2.y;
            r6 += w * p3.x; r7 += w * p3.y;
        }
    }

    const float inv = 0.25f / (ssum + 1e-16f);
    r0 *= inv; r1 *= inv; r2 *= inv; r3 *= inv;
    r4 *= inv; r5 *= inv; r6 *= inv; r7 *= inv;

#pragma unroll
    for (int off = 16; off < 64; off <<= 1) {
        r0 += __shfl_xor(r0, off); r1 += __shfl_xor(r1, off);
        r2 += __shfl_xor(r2, off); r3 += __shfl_xor(r3, off);
        r4 += __shfl_xor(r4, off); r5 += __shfl_xor(r5, off);
        r6 += __shfl_xor(r6, off); r7 += __shfl_xor(r7, off);
    }

    if (h == 0) {
        const int c = t * 8;
        const float4 x0 = *(const float4*)(x + (size_t)n * CC + c);
        const float4 x1 = *(const float4*)(x + (size_t)n * CC + c + 4);
        const float4 b0 = *(const float4*)(bias + c);
        const float4 b1 = *(const float4*)(bias + c + 4);
        float4 o0, o1;
        o0.x = 0.8f * x0.x + 0.2f * (r0 + b0.x);
        o0.y = 0.8f * x0.y + 0.2f * (r1 + b0.y);
        o0.z = 0.8f * x0.z + 0.2f * (r2 + b0.z);
        o0.w = 0.8f * x0.w + 0.2f * (r3 + b0.w);
        o1.x = 0.8f * x1.x + 0.2f * (r4 + b1.x);
        o1.y = 0.8f * x1.y + 0.2f * (r5 + b1.y);
        o1.z = 0.8f * x1.z + 0.2f * (r6 + b1.z);
        o1.w = 0.8f * x1.w + 0.2f * (r7 + b1.w);
        *(float4*)(out + (size_t)n * CC + c)     = o0;
        *(float4*)(out + (size_t)n * CC + c + 4) = o1;
    }
}

extern "C" void kernel_launch(void* const* d_in, const int* in_sizes, int n_in,
                              void* d_out, int out_size, void* d_ws, size_t ws_size,
                              hipStream_t stream)
{
    const float* x     = (const float*)d_in[0];
    const int*   ei    = (const int*)d_in[1];
    const float* W     = (const float*)d_in[2];
    const float* att_s = (const float*)d_in[3];
    const float* att_d = (const float*)d_in[4];
    const float* bias  = (const float*)d_in[5];
    float* out = (float*)d_out;

    char* p = (char*)d_ws;
    unsigned char*  xhq   = (unsigned char*)p;  p += (size_t)NN * HCW;      // 25.6 MB
    unsigned short* wt    = (unsigned short*)p; p += (size_t)HCW * CC * 2;  // 128 KB
    float*          asrc  = (float*)p;          p += (size_t)NN * HH * 4;
    float*          adst  = (float*)p;          p += (size_t)NN * HH * 4;
    int*            deg   = (int*)p;            p += (size_t)NN * 4;        // zeroed
    unsigned short* pos   = (unsigned short*)p; p += (size_t)TOT * 2;
    int*            rowptr= (int*)p;            p += (size_t)(NN + 1) * 4;
    int*            csr_s = (int*)p;            p += (size_t)TOT * 4;
    int*            part  = (int*)p;            p += (size_t)SCAN_B * 4;

    hipMemsetAsync(deg, 0, (size_t)NN * 4, stream);

    k_prep_w<<<(HCW * CC + 255) / 256, 256, 0, stream>>>(W, wt);
    k_fat<<<GEMB + CNTB, 512, 0, stream>>>(x, wt, att_s, att_d, ei, xhq, asrc, adst, deg, pos);
    s_part<<<SCAN_B, 256, 0, stream>>>(deg, part);
    s_apply<<<SCAN_B, 256, 0, stream>>>(deg, part, rowptr);
    k_scatter<<<(TOT + 255) / 256, 256, 0, stream>>>(ei, rowptr, pos, csr_s);
    {
        const long long threads = (long long)NN * 64;
        const int blocks = (int)((threads + 255) / 256);
        k_gather<<<blocks, 256, 0, stream>>>(rowptr, csr_s, asrc, adst, xhq, x, bias, out);
    }
}

// Round 13
// 157.987 us; speedup vs baseline: 1.1405x; 1.0295x over previous
//
#include <hip/hip_runtime.h>
#include <math.h>

#define NN 50000
#define EE 800000
#define TOT (EE + NN)          // 850000 edges incl. self loops
#define CC 128
#define HH 4
#define HCW 512                // H*C
#define SCAN_B 196             // ceil(NN/256)
#define RB 64                  // rows per gemm block
#define GEMB ((NN + RB - 1) / RB)        // 782 gemm blocks
#define CNTB ((TOT + 511) / 512)         // 1661 count blocks
#define LOG2E 1.442695040888963f

typedef short s16x8 __attribute__((ext_vector_type(8)));
typedef float f32x4 __attribute__((ext_vector_type(4)));
typedef float f32x2 __attribute__((ext_vector_type(2)));

// fp32 -> bf16 bits, round-to-nearest-even
__device__ __forceinline__ unsigned f2bf(float f) {
    unsigned u = __float_as_uint(f);
    return (u + 0x7fffu + ((u >> 16) & 1u)) >> 16;
}

// -------- P2: W [128][512] fp32 -> Wt [512][128] bf16 --------
__global__ __launch_bounds__(256) void k_prep_w(
    const float* __restrict__ W, unsigned short* __restrict__ wt)
{
    const int i = blockIdx.x * 256 + threadIdx.x;   // i = c*128 + k
    if (i >= HCW * CC) return;
    const int c = i >> 7, k = i & 127;
    wt[i] = (unsigned short)f2bf(W[(size_t)k * HCW + c]);
}

// -------- K1 (fat): blocks [0,GEMB) = MFMA gemm -> fp8 xh + fused att;
//                    blocks [GEMB, GEMB+CNTB) = degree count --------
// NOTE: epilogue kept in r9/r11 shape — hoisting att coeffs spills (r10).
// asrc/adst are stored pre-scaled by log2(e) so the gather uses exp2 directly.
__global__ __launch_bounds__(512, 4) void k_fat(
    const float* __restrict__ x,             // [NN][128] fp32
    const unsigned short* __restrict__ wt,   // [512][128] bf16 = W^T
    const float* __restrict__ att_s, const float* __restrict__ att_d,
    const int* __restrict__ ei,
    unsigned char* __restrict__ xhq,         // [NN][512] fp8 e4m3
    float* __restrict__ asrc, float* __restrict__ adst,
    int* __restrict__ deg, unsigned short* __restrict__ pos)
{
    __shared__ unsigned short xs[RB][CC + 8];   // 64x136 bf16
    __shared__ float red[8][2][16];

    if (blockIdx.x >= GEMB) {
        // ---- degree count part ----
        const int e = (blockIdx.x - GEMB) * 512 + threadIdx.x;
        if (e < TOT) {
            const int d = (e < EE) ? ei[EE + e] : (e - EE);
            pos[e] = (unsigned short)atomicAdd(deg + d, 1);
        }
        return;
    }

    // ---- gemm part ----
    const int r0   = blockIdx.x * RB;
    const int wv   = threadIdx.x >> 6;
    const int h    = wv >> 1;
    const int half = wv & 1;
    const int lane = threadIdx.x & 63;
    const int lrow = lane & 15;
    const int kg   = lane >> 4;
    const int n_base = h * 128 + half * 64;

    for (int i = threadIdx.x; i < RB * 32; i += 512) {
        const int row = i >> 5;
        const int c4  = (i & 31) * 4;
        const int grow = r0 + row;
        float4 v = make_float4(0.f, 0.f, 0.f, 0.f);
        if (grow < NN) v = *(const float4*)(x + (size_t)grow * CC + c4);
        uint2 o;
        o.x = f2bf(v.x) | (f2bf(v.y) << 16);
        o.y = f2bf(v.z) | (f2bf(v.w) << 16);
        *(uint2*)(&xs[row][c4]) = o;
    }

    s16x8 wf0[4], wf1[4], wf2[4], wf3[4];
#pragma unroll
    for (int kk = 0; kk < 4; ++kk) {
        wf0[kk] = *(const s16x8*)(wt + (size_t)(n_base + 0  + lrow) * CC + kg * 8 + kk * 32);
        wf1[kk] = *(const s16x8*)(wt + (size_t)(n_base + 16 + lrow) * CC + kg * 8 + kk * 32);
        wf2[kk] = *(const s16x8*)(wt + (size_t)(n_base + 32 + lrow) * CC + kg * 8 + kk * 32);
        wf3[kk] = *(const s16x8*)(wt + (size_t)(n_base + 48 + lrow) * CC + kg * 8 + kk * 32);
    }
    __syncthreads();

    const int cbase = h * CC + half * 64 + kg * 4;

    for (int rt = 0; rt < 4; ++rt) {
        f32x4 acc0 = {0.f, 0.f, 0.f, 0.f};
        f32x4 acc1 = {0.f, 0.f, 0.f, 0.f};
        f32x4 acc2 = {0.f, 0.f, 0.f, 0.f};
        f32x4 acc3 = {0.f, 0.f, 0.f, 0.f};
#pragma unroll
        for (int kk = 0; kk < 4; ++kk) {
            const s16x8 b = *(const s16x8*)(&xs[rt * 16 + lrow][kg * 8 + kk * 32]);
            acc0 = __builtin_amdgcn_mfma_f32_16x16x32_bf16(wf0[kk], b, acc0, 0, 0, 0);
            acc1 = __builtin_amdgcn_mfma_f32_16x16x32_bf16(wf1[kk], b, acc1, 0, 0, 0);
            acc2 = __builtin_amdgcn_mfma_f32_16x16x32_bf16(wf2[kk], b, acc2, 0, 0, 0);
            acc3 = __builtin_amdgcn_mfma_f32_16x16x32_bf16(wf3[kk], b, acc3, 0, 0, 0);
        }

        const int grow = r0 + rt * 16 + lrow;
        if (grow < NN) {
            // pack each 4-channel fragment into 4 fp8 bytes (one dword)
            unsigned char* orow = xhq + (size_t)grow * HCW + n_base + kg * 4;
            unsigned u;
            u = __builtin_amdgcn_cvt_pk_fp8_f32(acc0[0], acc0[1], 0u, false);
            u = __builtin_amdgcn_cvt_pk_fp8_f32(acc0[2], acc0[3], u, true);
            *(unsigned*)(orow) = u;
            u = __builtin_amdgcn_cvt_pk_fp8_f32(acc1[0], acc1[1], 0u, false);
            u = __builtin_amdgcn_cvt_pk_fp8_f32(acc1[2], acc1[3], u, true);
            *(unsigned*)(orow + 16) = u;
            u = __builtin_amdgcn_cvt_pk_fp8_f32(acc2[0], acc2[1], 0u, false);
            u = __builtin_amdgcn_cvt_pk_fp8_f32(acc2[2], acc2[3], u, true);
            *(unsigned*)(orow + 32) = u;
            u = __builtin_amdgcn_cvt_pk_fp8_f32(acc3[0], acc3[1], 0u, false);
            u = __builtin_amdgcn_cvt_pk_fp8_f32(acc3[2], acc3[3], u, true);
            *(unsigned*)(orow + 48) = u;
        }

        float ps, pd;
        {
            const float4 c0 = *(const float4*)(att_s + cbase);
            const float4 c1 = *(const float4*)(att_s + cbase + 16);
            const float4 c2 = *(const float4*)(att_s + cbase + 32);
            const float4 c3 = *(const float4*)(att_s + cbase + 48);
            ps = acc0[0]*c0.x + acc0[1]*c0.y + acc0[2]*c0.z + acc0[3]*c0.w
               + acc1[0]*c1.x + acc1[1]*c1.y + acc1[2]*c1.z + acc1[3]*c1.w
               + acc2[0]*c2.x + acc2[1]*c2.y + acc2[2]*c2.z + acc2[3]*c2.w
               + acc3[0]*c3.x + acc3[1]*c3.y + acc3[2]*c3.z + acc3[3]*c3.w;
        }
        {
            const float4 c0 = *(const float4*)(att_d + cbase);
            const float4 c1 = *(const float4*)(att_d + cbase + 16);
            const float4 c2 = *(const float4*)(att_d + cbase + 32);
            const float4 c3 = *(const float4*)(att_d + cbase + 48);
            pd = acc0[0]*c0.x + acc0[1]*c0.y + acc0[2]*c0.z + acc0[3]*c0.w
               + acc1[0]*c1.x + acc1[1]*c1.y + acc1[2]*c1.z + acc1[3]*c1.w
               + acc2[0]*c2.x + acc2[1]*c2.y + acc2[2]*c2.z + acc2[3]*c2.w
               + acc3[0]*c3.x + acc3[1]*c3.y + acc3[2]*c3.z + acc3[3]*c3.w;
        }
        ps += __shfl_xor(ps, 16); ps += __shfl_xor(ps, 32);
        pd += __shfl_xor(pd, 16); pd += __shfl_xor(pd, 32);
        red[wv][0][lrow] = ps;
        red[wv][1][lrow] = pd;
        __syncthreads();
        if (threadIdx.x < 128) {
            const int t     = threadIdx.x & 15;
            const int hh    = (threadIdx.x >> 4) & 3;
            const int which = threadIdx.x >> 6;
            const int row   = r0 + rt * 16 + t;
            if (row < NN) {
                const float v = red[hh * 2][which][t] + red[hh * 2 + 1][which][t];
                float* dst = which ? adst : asrc;
                dst[row * HH + hh] = v * LOG2E;   // pre-scale for exp2 in gather
            }
        }
        __syncthreads();
    }
}

// -------- scan: per-block partial sums --------
__global__ __launch_bounds__(256) void s_part(
    const int* __restrict__ deg, int* __restrict__ part)
{
    const int idx = blockIdx.x * 256 + threadIdx.x;
    int v = (idx < NN) ? deg[idx] : 0;
#pragma unroll
    for (int off = 1; off < 64; off <<= 1) v += __shfl_xor(v, off);
    __shared__ int sm[4];
    if ((threadIdx.x & 63) == 0) sm[threadIdx.x >> 6] = v;
    __syncthreads();
    if (threadIdx.x == 0) part[blockIdx.x] = sm[0] + sm[1] + sm[2] + sm[3];
}

// -------- scan apply (mid-scan inlined) --------
__global__ __launch_bounds__(256) void s_apply(
    const int* __restrict__ deg, const int* __restrict__ part,
    int* __restrict__ rowptr)
{
    __shared__ int sm[256];
    __shared__ int ws[4];
    const int t   = threadIdx.x;
    const int bid = blockIdx.x;

    int pv = (t < SCAN_B && t < bid) ? part[t] : 0;
#pragma unroll
    for (int off = 1; off < 64; off <<= 1) pv += __shfl_xor(pv, off);
    if ((t & 63) == 0) ws[t >> 6] = pv;
    __syncthreads();
    const int poff = ws[0] + ws[1] + ws[2] + ws[3];

    const int idx = bid * 256 + t;
    const int v = (idx < NN) ? deg[idx] : 0;
    sm[t] = v;
    __syncthreads();
    for (int off = 1; off < 256; off <<= 1) {
        int u = (t >= off) ? sm[t - off] : 0;
        __syncthreads();
        sm[t] += u;
        __syncthreads();
    }
    if (idx < NN) rowptr[idx] = poff + sm[t] - v;   // exclusive
    if (bid == 0 && t == 0) rowptr[NN] = TOT;
}

// -------- K4: atomic-free scatter of src ids into dst-sorted CSR --------
__global__ __launch_bounds__(256) void k_scatter(
    const int* __restrict__ ei, const int* __restrict__ rowptr,
    const unsigned short* __restrict__ pos, int* __restrict__ csr_s)
{
    const int e = blockIdx.x * 256 + threadIdx.x;
    if (e >= TOT) return;
    int s, d;
    if (e < EE) { s = ei[e]; d = ei[EE + e]; } else { s = d = e - EE; }
    csr_s[rowptr[d] + pos[e]] = s;
}

// -------- K5: single-pass softmax + fp8 gather + residual (scalarized) ----
// one wave per node; lane = h*16 + t owns channels lane*8..+7.
// All edge ids / row bases are wave-uniform -> readfirstlane to SGPR:
// gathers become saddr + loop-invariant voffset, no per-edge vector addr math.
__global__ __launch_bounds__(256) void k_gather(
    const int* __restrict__ rowptr, const int* __restrict__ csr_s,
    const float* __restrict__ asrc, const float* __restrict__ adst,
    const unsigned char* __restrict__ xhq, const float* __restrict__ x,
    const float* __restrict__ bias, float* __restrict__ out)
{
    const int gtid = blockIdx.x * 256 + threadIdx.x;
    const int n    = __builtin_amdgcn_readfirstlane(gtid >> 6);   // wave-uniform
    const int lane = threadIdx.x & 63;
    if (n >= NN) return;
    const int h = lane >> 4;
    const int t = lane & 15;

    const int beg = __builtin_amdgcn_readfirstlane(rowptr[n]);
    const int end = __builtin_amdgcn_readfirstlane(rowptr[n + 1]);
    const float ad = adst[n * HH + h];
    const int voff = lane << 3;            // byte offset within a 512B xh row

    float ssum = 0.f;
    f32x2 a0 = {0.f, 0.f}, a1 = {0.f, 0.f}, a2 = {0.f, 0.f}, a3 = {0.f, 0.f};

    int j = beg;
    // ---- exact 8-wide batches, scalar bases ----
    for (; j + 8 <= end; j += 8) {
        int ss[8];
#pragma unroll
        for (int u = 0; u < 8; ++u)
            ss[u] = __builtin_amdgcn_readfirstlane(csr_s[j + u]);
        uint2 qq[8];
#pragma unroll
        for (int u = 0; u < 8; ++u)
            qq[u] = *(const uint2*)(xhq + ((size_t)(unsigned)ss[u] << 9) + voff);
        float ww[8];
#pragma unroll
        for (int u = 0; u < 8; ++u) {
            float e = asrc[(ss[u] << 2) + h] + ad;
            e = fmaxf(e, 0.2f * e);        // leaky_relu, exact
            ww[u] = exp2f(e);
            ssum += ww[u];
        }
#pragma unroll
        for (int u = 0; u < 8; ++u) {
            const f32x2 p0 = __builtin_amdgcn_cvt_pk_f32_fp8(qq[u].x, false);
            const f32x2 p1 = __builtin_amdgcn_cvt_pk_f32_fp8(qq[u].x, true);
            const f32x2 p2 = __builtin_amdgcn_cvt_pk_f32_fp8(qq[u].y, false);
            const f32x2 p3 = __builtin_amdgcn_cvt_pk_f32_fp8(qq[u].y, true);
            const f32x2 wv = {ww[u], ww[u]};
            a0 += wv * p0; a1 += wv * p1; a2 += wv * p2; a3 += wv * p3;
        }
    }
    // ---- tail: up to two predicated 4-wide batches (indices still uniform) --
    for (int base = j; base < end; base += 4) {
        int ss[4];
#pragma unroll
        for (int u = 0; u < 4; ++u) {
            const int idx = (base + u < end) ? (base + u) : (end - 1);
            ss[u] = __builtin_amdgcn_readfirstlane(csr_s[idx]);
        }
        uint2 qq[4];
#pragma unroll
        for (int u = 0; u < 4; ++u)
            qq[u] = *(const uint2*)(xhq + ((size_t)(unsigned)ss[u] << 9) + voff);
        float ww[4];
#pragma unroll
        for (int u = 0; u < 4; ++u) {
            float e = asrc[(ss[u] << 2) + h] + ad;
            e = fmaxf(e, 0.2f * e);
            float w = exp2f(e);
            w = (base + u < end) ? w : 0.f;
            ww[u] = w;
            ssum += w;
        }
#pragma unroll
        for (int u = 0; u < 4; ++u) {
            const f32x2 p0 = __builtin_amdgcn_cvt_pk_f32_fp8(qq[u].x, false);
            const f32x2 p1 = __builtin_amdgcn_cvt_pk_f32_fp8(qq[u].x, true);
            const f32x2 p2 = __builtin_amdgcn_cvt_pk_f32_fp8(qq[u].y, false);
            const f32x2 p3 = __builtin_amdgcn_cvt_pk_f32_fp8(qq[u].y, true);
            const f32x2 wv = {ww[u], ww[u]};
            a0 += wv * p0; a1 += wv * p1; a2 += wv * p2; a3 += wv * p3;
        }
    }

    const float inv = 0.25f / (ssum + 1e-16f);
    const f32x2 iv = {inv, inv};
    a0 *= iv; a1 *= iv; a2 *= iv; a3 *= iv;
    float r0 = a0.x, r1 = a0.y, r2 = a1.x, r3 = a1.y;
    float r4 = a2.x, r5 = a2.y, r6 = a3.x, r7 = a3.y;

    // sum across the 4 head groups (lane bits 4..5)
#pragma unroll
    for (int off = 16; off < 64; off <<= 1) {
        r0 += __shfl_xor(r0, off); r1 += __shfl_xor(r1, off);
        r2 += __shfl_xor(r2, off); r3 += __shfl_xor(r3, off);
        r4 += __shfl_xor(r4, off); r5 += __shfl_xor(r5, off);
        r6 += __shfl_xor(r6, off); r7 += __shfl_xor(r7, off);
    }

    if (h == 0) {
        const int c = t * 8;
        const float4 x0 = *(const float4*)(x + (size_t)n * CC + c);
        const float4 x1 = *(const float4*)(x + (size_t)n * CC + c + 4);
        const float4 b0 = *(const float4*)(bias + c);
        const float4 b1 = *(const float4*)(bias + c + 4);
        float4 o0, o1;
        o0.x = 0.8f * x0.x + 0.2f * (r0 + b0.x);
        o0.y = 0.8f * x0.y + 0.2f * (r1 + b0.y);
        o0.z = 0.8f * x0.z + 0.2f * (r2 + b0.z);
        o0.w = 0.8f * x0.w + 0.2f * (r3 + b0.w);
        o1.x = 0.8f * x1.x + 0.2f * (r4 + b1.x);
        o1.y = 0.8f * x1.y + 0.2f * (r5 + b1.y);
        o1.z = 0.8f * x1.z + 0.2f * (r6 + b1.z);
        o1.w = 0.8f * x1.w + 0.2f * (r7 + b1.w);
        *(float4*)(out + (size_t)n * CC + c)     = o0;
        *(float4*)(out + (size_t)n * CC + c + 4) = o1;
    }
}

extern "C" void kernel_launch(void* const* d_in, const int* in_sizes, int n_in,
                              void* d_out, int out_size, void* d_ws, size_t ws_size,
                              hipStream_t stream)
{
    const float* x     = (const float*)d_in[0];
    const int*   ei    = (const int*)d_in[1];
    const float* W     = (const float*)d_in[2];
    const float* att_s = (const float*)d_in[3];
    const float* att_d = (const float*)d_in[4];
    const float* bias  = (const float*)d_in[5];
    float* out = (float*)d_out;

    char* p = (char*)d_ws;
    unsigned char*  xhq   = (unsigned char*)p;  p += (size_t)NN * HCW;      // 25.6 MB
    unsigned short* wt    = (unsigned short*)p; p += (size_t)HCW * CC * 2;  // 128 KB
    float*          asrc  = (float*)p;          p += (size_t)NN * HH * 4;
    float*          adst  = (float*)p;          p += (size_t)NN * HH * 4;
    int*            deg   = (int*)p;            p += (size_t)NN * 4;        // zeroed
    unsigned short* pos   = (unsigned short*)p; p += (size_t)TOT * 2;
    int*            rowptr= (int*)p;            p += (size_t)(NN + 1) * 4;
    int*            csr_s = (int*)p;            p += (size_t)TOT * 4;
    int*            part  = (int*)p;            p += (size_t)SCAN_B * 4;

    hipMemsetAsync(deg, 0, (size_t)NN * 4, stream);

    k_prep_w<<<(HCW * CC + 255) / 256, 256, 0, stream>>>(W, wt);
    k_fat<<<GEMB + CNTB, 512, 0, stream>>>(x, wt, att_s, att_d, ei, xhq, asrc, adst, deg, pos);
    s_part<<<SCAN_B, 256, 0, stream>>>(deg, part);
    s_apply<<<SCAN_B, 256, 0, stream>>>(deg, part, rowptr);
    k_scatter<<<(TOT + 255) / 256, 256, 0, stream>>>(ei, rowptr, pos, csr_s);
    {
        const long long threads = (long long)NN * 64;
        const int blocks = (int)((threads + 255) / 256);
        k_gather<<<blocks, 256, 0, stream>>>(rowptr, csr_s, asrc, adst, xhq, x, bias, out);
    }
}